// Round 15
// baseline (18.786 us; speedup 1.0000x reference)
//
#include <hip/hip_runtime.h>
#include <math.h>

typedef short bf16x8 __attribute__((ext_vector_type(8)));
typedef float f32x4 __attribute__((ext_vector_type(4)));
typedef unsigned short u16;
typedef unsigned int u32;

// ws byte offsets: QT (B,N,32) bf16, KT (B,N,32) bf16,
// VW (B,32,1032) bf16 (1024 + 8 pad per kd row, pad zeroed by proj),
// QXY (B,N,2) f32, KXY (B,N,2) f32
#define WS_QT  0
#define WS_KT  1048576
#define WS_VW  2097152
#define WS_QXY 3153920
#define WS_KXY 3284992
#define VWS    1032

__device__ __forceinline__ u32 f2bf(float f) {
    u32 u = __float_as_uint(f);
    u += 0x7fffu + ((u >> 16) & 1u);
    return u >> 16;
}
__device__ __forceinline__ u32 pk2(float a, float b) {
    return f2bf(a) | (f2bf(b) << 16);
}

union U4H { uint4 u; bf16x8 h; };

// ---------- projections as MFMA GEMM: 2048 one-wave blocks ----------
// j-tile split: h=0 blocks do jt 0-3 (QT,KT), h=1 blocks do jt 4-6 (VW,XY)
// -> 2 waves/SIMD (vs 1), per-wave chain halves. Per-jt math unchanged.
__global__ __launch_bounds__(64) void proj_kernel(
    const float* __restrict__ x,
    const float* __restrict__ Wq, const float* __restrict__ Wk,
    const float* __restrict__ Wv, const float* __restrict__ Wqxy,
    const float* __restrict__ Wkxy, char* __restrict__ wsb)
{
    u16* QT = (u16*)(wsb + WS_QT);
    u16* KT = (u16*)(wsb + WS_KT);
    u16* VW = (u16*)(wsb + WS_VW);
    float* QXY = (float*)(wsb + WS_QXY);
    float* KXY = (float*)(wsb + WS_KXY);

    int l = threadIdx.x;
    int g = l >> 4, l15 = l & 15;
    int bid = blockIdx.x;
    int xcd = bid & 7, j = bid >> 3;             // bijective XCD swizzle
    int b = (xcd << 1) + (j >> 7);               // 2 batches per XCD
    int h = j & 1;                               // j-tile half
    int n0 = ((j >> 1) & 63) << 4;

    bf16x8 ah[2], al[2];
    #pragma unroll
    for (int ks = 0; ks < 2; ks++) {
        float av[8];
        #pragma unroll
        for (int i = 0; i < 8; i++)
            av[i] = x[(((b << 6) + (ks << 5) + (g << 3) + i) << 10) + n0 + l15];
        #pragma unroll
        for (int i = 0; i < 8; i++) {
            u32 hb = f2bf(av[i]);
            float rr = av[i] - __uint_as_float(hb << 16);
            ah[ks][i] = (short)hb;
            al[ks][i] = (short)f2bf(rr);
        }
    }

    auto do_jt = [&](int jt) {
        f32x4 acc = {0.f, 0.f, 0.f, 0.f};
        #pragma unroll
        for (int ks = 0; ks < 2; ks++) {
            float wv[8];
            #pragma unroll
            for (int i = 0; i < 8; i++) wv[i] = 0.f;
            if (jt < 6) {
                const float* wbase = (jt < 2) ? Wq : (jt < 4) ? Wk : Wv;
                const float* wr = wbase + ((((jt & 1) << 4) + l15) << 6)
                                        + (ks << 5) + (g << 3);
                float4 wa = *(const float4*)wr, wb = *(const float4*)(wr + 4);
                wv[0] = wa.x; wv[1] = wa.y; wv[2] = wa.z; wv[3] = wa.w;
                wv[4] = wb.x; wv[5] = wb.y; wv[6] = wb.z; wv[7] = wb.w;
            } else if (l15 < 4) {
                const float* wr = ((l15 < 2) ? (Wqxy + (l15 << 6))
                                             : (Wkxy + ((l15 - 2) << 6)))
                                  + (ks << 5) + (g << 3);
                float4 wa = *(const float4*)wr, wb = *(const float4*)(wr + 4);
                wv[0] = wa.x; wv[1] = wa.y; wv[2] = wa.z; wv[3] = wa.w;
                wv[4] = wb.x; wv[5] = wb.y; wv[6] = wb.z; wv[7] = wb.w;
            }
            bf16x8 wh, wl;
            #pragma unroll
            for (int i = 0; i < 8; i++) {
                u32 hb = f2bf(wv[i]);
                float rr = wv[i] - __uint_as_float(hb << 16);
                wh[i] = (short)hb;
                wl[i] = (short)f2bf(rr);
            }
            acc = __builtin_amdgcn_mfma_f32_16x16x32_bf16(ah[ks], wh, acc, 0, 0, 0);
            acc = __builtin_amdgcn_mfma_f32_16x16x32_bf16(al[ks], wh, acc, 0, 0, 0);
            acc = __builtin_amdgcn_mfma_f32_16x16x32_bf16(ah[ks], wl, acc, 0, 0, 0);
        }
        if (jt < 2) {
            #pragma unroll
            for (int r = 0; r < 4; r++)
                QT[(((b << 10) + n0 + (g << 2) + r) << 5) + (jt << 4) + l15]
                    = (u16)f2bf(acc[r]);
        } else if (jt < 4) {
            #pragma unroll
            for (int r = 0; r < 4; r++)
                KT[(((b << 10) + n0 + (g << 2) + r) << 5) + ((jt - 2) << 4) + l15]
                    = (u16)f2bf(acc[r]);
        } else if (jt < 6) {
            int kd = ((jt - 4) << 4) + l15;
            uint2 d = make_uint2(pk2(acc[0], acc[1]), pk2(acc[2], acc[3]));
            *(uint2*)&VW[((b << 5) + kd) * VWS + n0 + (g << 2)] = d;
        } else {
            if (l15 < 2) {
                #pragma unroll
                for (int r = 0; r < 4; r++)
                    QXY[(((b << 10) + n0 + (g << 2) + r) << 1) + l15] = acc[r];
            } else if (l15 < 4) {
                #pragma unroll
                for (int r = 0; r < 4; r++)
                    KXY[(((b << 10) + n0 + (g << 2) + r) << 1) + (l15 - 2)] = acc[r];
            }
        }
    };

    if (h == 0) {
        #pragma unroll
        for (int jt = 0; jt < 4; jt++) do_jt(jt);
    } else {
        #pragma unroll
        for (int jt = 4; jt < 7; jt++) do_jt(jt);
        if (((j >> 1) & 63) == 63 && l < 32)
            *(uint4*)&VW[((b << 5) + l) * VWS + 1024] = make_uint4(0, 0, 0, 0);
    }
}

// ---------- attention: 256 blocks = (b, 16x4-query tile); wave = 16 queries ----
// Round-14 structure, but K fragments are read DIRECTLY from global KT in the
// QK loop (no kfr staging; values bit-identical via the same OOB clamp).
// LDS 35.5KB -> 4 blocks/CU, 4 waves/SIMD (launch_bounds(256,4)).
// O-transpose aliases vfr (dead after PV) behind a barrier.
__global__ __launch_bounds__(256, 4) void attn_kernel(
    const char* __restrict__ wsb, const float* __restrict__ Wout,
    float* __restrict__ out)
{
    const u16* QT = (const u16*)(wsb + WS_QT);
    const u16* KT = (const u16*)(wsb + WS_KT);
    const u16* VW = (const u16*)(wsb + WS_VW);
    const float* QXY = (const float*)(wsb + WS_QXY);
    const float* KXY = (const float*)(wsb + WS_KXY);

    // flat LDS: vfr 0..14335 (14 pairs), kxy u32 at 14336..16127,
    // wfr 16128..18175. 36352 B total.
    __shared__ __align__(16) u16 smem[18176];
    u16* vfr = smem;
    u32* kxyb = (u32*)(smem + 14336);
    u16* wfr = smem + 16128;
    u16* o_l = smem;                 // aliases vfr after PV (barrier-protected)

    int tid = threadIdx.x, bid = blockIdx.x;
    int xcd = bid & 7, j = bid >> 3;             // bijective XCD swizzle
    int b = (xcd << 1) + (j >> 4);
    int t4 = j & 15;
    int qy0 = (t4 >> 3) << 4, qx0 = (t4 & 7) << 2;
    int ry0 = qy0 - 6, rx0 = qx0 - 6;

    // ---- stage V fragments: 3584 granules, d -> (p,kd,g2,pair m=d>>8)
    #pragma unroll
    for (int i = 0; i < 14; i++) {
        int d = tid + (i << 8);
        int p = d & 1, kd = (d >> 1) & 31, g2 = (d >> 6) & 3, m = d >> 8;
        int ky = ry0 + (m << 1) + p;
        int n = ky * 32 + rx0 + (g2 << 2);
        if ((u32)ky > 31u) n = 0;               // masked rows -> finite data
        const u32* s = (const u32*)(VW + ((b << 5) + kd) * VWS + n);
        *(uint2*)&vfr[d << 2] = make_uint2(s[0], s[1]);
    }
    // ---- stage kxy hi/lo packed per slot (448 slots)
    for (int i = tid; i < 448; i += 256) {
        int n2 = (ry0 + (i >> 4)) * 32 + rx0 + (i & 15);
        n2 = max(0, min(1023, n2));
        float2 f = *(const float2*)(KXY + (((b << 10) + n2) << 1));
        u32 h0 = f2bf(f.x), h1 = f2bf(f.y);
        float r0 = f.x - __uint_as_float(h0 << 16);
        float r1 = f.y - __uint_as_float(h1 << 16);
        kxyb[(i << 1)]     = h0 | (h1 << 16);
        kxyb[(i << 1) + 1] = f2bf(r0) | (f2bf(r1) << 16);
    }
    // ---- stage Wout^T fragments
    {
        int nt = tid >> 6, l = tid & 63;
        int cc = (nt << 4) + (l & 15);
        const float* wsrc = Wout + (cc << 5) + ((l >> 4) << 3);
        uint4 dw;
        dw.x = pk2(wsrc[0], wsrc[1]); dw.y = pk2(wsrc[2], wsrc[3]);
        dw.z = pk2(wsrc[4], wsrc[5]); dw.w = pk2(wsrc[6], wsrc[7]);
        *(uint4*)&wfr[tid << 3] = dw;
    }

    // ---- per-lane query setup (global reads, issued pre-barrier)
    int w = tid >> 6, ll = tid & 63;
    int lq = ll & 15, g = ll >> 4;
    int qrl = lq >> 2, qcol = lq & 3;           // query row/col within wave
    int nq = (qy0 + (w << 2) + qrl) * 32 + qx0 + qcol;
    uint4 bqu = *(const uint4*)(QT + (((b << 10) + nq) << 5) + (g << 3));
    float2 qv = *(const float2*)(QXY + (((b << 10) + nq) << 1));
    u32 qh0 = f2bf(qv.x), qh1 = f2bf(qv.y);
    float qr0 = qv.x - __uint_as_float(qh0 << 16);
    float qr1 = qv.y - __uint_as_float(qh1 << 16);
    u32 qhp = qh0 | (qh1 << 16);
    u32 qlp = f2bf(qr0) | (f2bf(qr1) << 16);
    uint4 bxyu = make_uint4(g == 0 ? qhp : 0, g == 0 ? qlp : 0,
                            g == 0 ? qhp : 0, 0);

    __syncthreads();

    // ---- QK^T (swapped) + xy MFMA; K fragments direct from global (L2-local)
    // acc[t][r] = S[slot=(4w+t)*16 + 4g+r][q=lq]
    f32x4 acc[16];
    #pragma unroll
    for (int t = 0; t < 16; t++) {
        int rr = (w << 2) + t;
        uint2 kp = *(const uint2*)&kxyb[((rr << 4) + lq) << 1];
        U4H axy; axy.u = make_uint4(g == 0 ? kp.x : 0, g == 0 ? kp.x : 0,
                                    g == 0 ? kp.y : 0, 0);
        U4H bxy; bxy.u = bxyu;
        f32x4 z = {0.f, 0.f, 0.f, 0.f};
        f32x4 a0 = __builtin_amdgcn_mfma_f32_16x16x32_bf16(axy.h, bxy.h, z, 0, 0, 0);
        int n2 = (ry0 + rr) * 32 + rx0 + lq;
        n2 = max(0, min(1023, n2));
        U4H ak; ak.u = *(const uint4*)(KT + (((b << 10) + n2) << 5) + (g << 3));
        U4H bq; bq.u = bqu;
        acc[t] = __builtin_amdgcn_mfma_f32_16x16x32_bf16(ak.h, bq.h, a0, 0, 0, 0);
    }

    // ---- mask + softmax: per-lane partials + cross-g combine (4 shuffles)
    int dx2a[4], kxa[4];
    #pragma unroll
    for (int r = 0; r < 4; r++) {
        int sc = (g << 2) + r;
        int kx = rx0 + sc;
        kxa[r] = (kx >= 0) && (kx < 32);
        int dx = sc - 6 - qcol;
        dx2a[r] = dx * dx;
    }
    float m = -1e30f;
    #pragma unroll
    for (int t = 0; t < 16; t++) {
        int ky = ry0 + (w << 2) + t;
        bool kyok = (ky >= 0) && (ky < 32);
        int dy = t - 6 - qrl, dy2 = dy * dy;
        #pragma unroll
        for (int r = 0; r < 4; r++) {
            bool ok = kyok && kxa[r] && (dy2 + dx2a[r] <= 36);
            acc[t][r] = ok ? acc[t][r] : -1e4f;
            m = fmaxf(m, acc[t][r]);
        }
    }
    m = fmaxf(m, __shfl_xor(m, 16, 64));
    m = fmaxf(m, __shfl_xor(m, 32, 64));

    float sum = 0.f;
    #pragma unroll
    for (int t = 0; t < 16; t++) {
        #pragma unroll
        for (int r = 0; r < 4; r++) {
            float e = __expf(acc[t][r] - m);
            acc[t][r] = e;
            sum += e;
        }
    }
    sum += __shfl_xor(sum, 16, 64);
    sum += __shfl_xor(sum, 32, 64);

    float rinv = 1.f / sum;
    #pragma unroll
    for (int t = 0; t < 16; t++) {
        #pragma unroll
        for (int r = 0; r < 4; r++) acc[t][r] *= rinv;   // pre-scale P (linear)
    }

    // ---- PV: k-block kk = even row pair m2 = 2w+kk -> A-frag lane-local
    f32x4 o0 = {0.f, 0.f, 0.f, 0.f}, o1 = {0.f, 0.f, 0.f, 0.f};
    #pragma unroll
    for (int kk = 0; kk < 8; kk++) {
        int m2 = (w << 1) + kk;
        U4H pa;
        pa.u = make_uint4(pk2(acc[2 * kk][0],     acc[2 * kk][1]),
                          pk2(acc[2 * kk][2],     acc[2 * kk][3]),
                          pk2(acc[2 * kk + 1][0], acc[2 * kk + 1][1]),
                          pk2(acc[2 * kk + 1][2], acc[2 * kk + 1][3]));
        U4H v0; v0.u = *(const uint4*)&vfr[((m2 << 7) + (g << 5) + lq) << 3];
        U4H v1; v1.u = *(const uint4*)&vfr[((m2 << 7) + (g << 5) + lq + 16) << 3];
        o0 = __builtin_amdgcn_mfma_f32_16x16x32_bf16(pa.h, v0.h, o0, 0, 0, 0);
        o1 = __builtin_amdgcn_mfma_f32_16x16x32_bf16(pa.h, v1.h, o1, 0, 0, 0);
    }

    // ---- O transpose via LDS (aliases vfr -> barrier first)
    __syncthreads();
    #pragma unroll
    for (int r = 0; r < 4; r++) {
        int q = (g << 2) + r;
        o_l[(w << 9) + (q << 5) + lq]      = (u16)f2bf(o0[r]);
        o_l[(w << 9) + (q << 5) + lq + 16] = (u16)f2bf(o1[r]);
    }
    __syncthreads();

    // ---- epilogue: Y = O * Wout^T, 4 column tiles, all 64 lanes active
    U4H aO; aO.u = *(const uint4*)&o_l[(w << 9) + (lq << 5) + (g << 3)];
    int nqb = (qy0 + (w << 2) + g) * 32 + qx0;   // row for q = 4g+r
    #pragma unroll
    for (int nt2 = 0; nt2 < 4; nt2++) {
        U4H bw; bw.u = *(const uint4*)&wfr[((nt2 << 6) + ll) << 3];
        f32x4 z = {0.f, 0.f, 0.f, 0.f};
        f32x4 y = __builtin_amdgcn_mfma_f32_16x16x32_bf16(aO.h, bw.h, z, 0, 0, 0);
        int cc = (nt2 << 4) + lq;
        #pragma unroll
        for (int r = 0; r < 4; r++)
            out[(((b << 6) + cc) << 10) + nqb + r] = y[r];
    }
}

extern "C" void kernel_launch(void* const* d_in, const int* in_sizes, int n_in,
                              void* d_out, int out_size, void* d_ws, size_t ws_size,
                              hipStream_t stream) {
    const float* x    = (const float*)d_in[0];
    const float* Wq   = (const float*)d_in[1];
    const float* Wk   = (const float*)d_in[2];
    const float* Wv   = (const float*)d_in[3];
    const float* Wqxy = (const float*)d_in[4];
    const float* Wkxy = (const float*)d_in[5];
    const float* Wout = (const float*)d_in[6];
    float* out = (float*)d_out;
    char* wsb  = (char*)d_ws;

    proj_kernel<<<2048, 64, 0, stream>>>(x, Wq, Wk, Wv, Wqxy, Wkxy, wsb);
    attn_kernel<<<256, 256, 0, stream>>>(wsb, Wout, out);
}